// Round 2
// baseline (432.731 us; speedup 1.0000x reference)
//
#include <hip/hip_runtime.h>
#include <math.h>

// Problem constants (fixed by the reference)
#define NB 32       // batch
#define ND 1024     // CTX_DIM
#define NC 2048     // CTX_SIZE
#define NH 1024     // HID
#define NSEQ 64     // seqlen
#define CCHUNK 16   // c-tile width per block
#define NCHUNK (NC / CCHUNK)   // 128 chunks per batch

// async global -> LDS, 16 B per lane, dest = uniform base + lane*16
#define GLD_TO_LDS(g, l)                                                     \
  __builtin_amdgcn_global_load_lds(                                          \
      (const __attribute__((address_space(1))) void*)(g),                    \
      (__attribute__((address_space(3))) void*)(l), 16, 0, 0)

// ---------------------------------------------------------------------------
// k1: v[b,d] = sum_h hidden[b,h] * W[h,d]   (bias is softmax-invariant: dropped)
// grid = 32 b * 8 dchunks(128) = 256 blocks, 128 threads. W fits in L2.
// ---------------------------------------------------------------------------
__global__ __launch_bounds__(128) void k1_v(const float* __restrict__ hidden,
                                            const float* __restrict__ W,
                                            float* __restrict__ v) {
  const int b = blockIdx.x >> 3;
  const int d = ((blockIdx.x & 7) << 7) + threadIdx.x;
  const float* hb = hidden + b * NH;
  float acc = 0.f;
#pragma unroll 16
  for (int h = 0; h < NH; ++h) acc += hb[h] * W[h * ND + d];
  v[b * ND + d] = acc;
}

// ---------------------------------------------------------------------------
// k2: fused scores + chunk-local softmax + weighted partial sums.
// One block per (b, c-chunk of 16). Tile [d][c] = 1024x16 fp32 = 64 KB LDS
// -> 2 blocks/CU so phases of one block hide under streaming of the other.
// Staging via global_load_lds dwordx4: tile word index == 4*tid exactly.
// Outputs: accp[bid][d] = sum_c exp(s_c - m)*ctx[b,d,c];  ml[bid] = {m, l}
// ---------------------------------------------------------------------------
__global__ __launch_bounds__(256) void k2_main(const float* __restrict__ ctx,
                                               const float* __restrict__ v,
                                               float* __restrict__ accp,
                                               float* __restrict__ ml) {
  __shared__ __align__(16) float tile[ND * CCHUNK];  // 64 KB, word = d*16 + c
  __shared__ __align__(16) float sred[256 * 4];      // 4 KB score partials
  __shared__ __align__(16) float pf[CCHUNK];         // softmax weights

  const int t = threadIdx.x;
  const int bid = blockIdx.x;
  const int b = bid >> 7;              // / NCHUNK
  const int c0 = (bid & (NCHUNK - 1)) << 4;
  const int dp = t >> 2;               // 0..63  (d = dp + 64*j)
  const int cg = t & 3;                // c-group of 4
  const int w = __builtin_amdgcn_readfirstlane(t >> 6);  // wave id, uniform

  // --- Phase A: issue all async tile loads (16 per wave, no VGPR round-trip)
  const float* gbase = ctx + (size_t)b * ND * NC + (size_t)dp * NC + c0 + cg * 4;
#pragma unroll
  for (int j = 0; j < 16; ++j) {
    GLD_TO_LDS(gbase + (size_t)(64 * NC) * j, tile + j * 1024 + (w << 8));
  }

  // preload v fragments straight from global (L2-hot, 4-lane broadcast)
  float vsr[16];
#pragma unroll
  for (int j = 0; j < 16; ++j) vsr[j] = v[b * ND + dp + 64 * j];

  __syncthreads();  // drains vmcnt for the global_load_lds

  // --- Phase B: score partials from the LDS tile (each thread re-reads its
  // own 16 B group: word 4*t + j*1024 -> 2-way bank alias = free)
  float4 s4 = make_float4(0.f, 0.f, 0.f, 0.f);
  const float* myw = tile + 4 * t;
#pragma unroll
  for (int j = 0; j < 16; ++j) {
    float4 x = *(const float4*)(myw + j * 1024);
    float vd = vsr[j];
    s4.x += x.x * vd; s4.y += x.y * vd; s4.z += x.z * vd; s4.w += x.w * vd;
  }
  *(float4*)(sred + 4 * t) = s4;   // flat idx 16*q + c  (q = t>>2)
  __syncthreads();

  // --- chunk-local softmax over 16 c's (lanes 0..15)
  if (t < 16) {
    float s = 0.f;
#pragma unroll
    for (int q = 0; q < 64; ++q) s += sred[16 * q + t];
    float mm = s;
#pragma unroll
    for (int off = 8; off; off >>= 1) mm = fmaxf(mm, __shfl_xor(mm, off, 16));
    float e = __expf(s - mm);
    float l = e;
#pragma unroll
    for (int off = 8; off; off >>= 1) l += __shfl_xor(l, off, 16);
    pf[t] = e;
    if (t == 0) { ml[bid * 2] = mm; ml[bid * 2 + 1] = l; }
  }
  __syncthreads();

  // --- Phase C: acc[d] = sum_c p[c] * tile[d*16+c], rotated bank groups
  float4 pr[4];
#pragma unroll
  for (int j = 0; j < 4; ++j)
    pr[j] = *(const float4*)(pf + (((j + t) & 3) << 2));

  float* ao = accp + (size_t)bid * ND;
#pragma unroll
  for (int k = 0; k < 4; ++k) {
    const int d = t + 256 * k;
    const float* tr = tile + d * CCHUNK;
    float a = 0.f;
#pragma unroll
    for (int j = 0; j < 4; ++j) {
      const int jr = (j + t) & 3;
      float4 x = *(const float4*)(tr + jr * 4);
      float4 pp = pr[j];
      a += x.x * pp.x + x.y * pp.y + x.z * pp.z + x.w * pp.w;
    }
    ao[d] = a;
  }
}

// ---------------------------------------------------------------------------
// k3: online-softmax combine across 128 chunks + broadcast to out[s,b,d].
// grid = 32 b * 8 d-slices(128) = 256 blocks, 128 threads (2 waves).
// ---------------------------------------------------------------------------
__global__ __launch_bounds__(128) void k3_combine_bcast(
    const float* __restrict__ accp, const float* __restrict__ ml,
    float* __restrict__ out) {
  __shared__ float sc[NCHUNK];
  __shared__ float red[4];
  const int b = blockIdx.x >> 3;
  const int dslice = blockIdx.x & 7;
  const int t = threadIdx.x;           // 0..127, chunk id
  const int w = t >> 6;

  float mi = ml[(b * NCHUNK + t) * 2];
  float li = ml[(b * NCHUNK + t) * 2 + 1];
  float mg = mi;
#pragma unroll
  for (int off = 32; off; off >>= 1) mg = fmaxf(mg, __shfl_xor(mg, off, 64));
  if ((t & 63) == 0) red[w] = mg;
  __syncthreads();
  mg = fmaxf(red[0], red[1]);
  float scale = __expf(mi - mg);
  float dpart = scale * li;
#pragma unroll
  for (int off = 32; off; off >>= 1) dpart += __shfl_xor(dpart, off, 64);
  sc[t] = scale;
  if ((t & 63) == 0) red[2 + w] = dpart;
  __syncthreads();
  const float sinv = 1.0f / (red[2] + red[3]);

  const int d = dslice * 128 + t;
  const float* ap = accp + (size_t)b * NCHUNK * ND + d;
  float acc = 0.f;
#pragma unroll 16
  for (int i = 0; i < NCHUNK; ++i) acc += sc[i] * ap[(size_t)i * ND];
  acc *= sinv;

  float* op = out + b * ND + d;
#pragma unroll 8
  for (int s = 0; s < NSEQ; ++s) op[(size_t)s * NB * ND] = acc;
}

extern "C" void kernel_launch(void* const* d_in, const int* in_sizes, int n_in,
                              void* d_out, int out_size, void* d_ws, size_t ws_size,
                              hipStream_t stream) {
  (void)in_sizes; (void)n_in; (void)out_size; (void)ws_size;
  // d_in: [0]=seqlen(int,1) [1]=hidden(1,32,1024) [2]=contextvects(32,1024,2048)
  //       [3]=W(1024,1024) [4]=b(1024)  -- bias unused (softmax-invariant).
  const float* hidden = (const float*)d_in[1];
  const float* ctxv   = (const float*)d_in[2];
  const float* W      = (const float*)d_in[3];
  float* out = (float*)d_out;

  char* ws = (char*)d_ws;
  float* v    = (float*)(ws);                    // 32*1024 fp32   = 128 KB
  float* ml   = (float*)(ws + 131072);           // 4096*2 fp32    =  32 KB
  float* accp = (float*)(ws + 131072 + 32768);   // 4096*1024 fp32 =  16 MB

  k1_v<<<256, 128, 0, stream>>>(hidden, W, v);
  k2_main<<<NB * NCHUNK, 256, 0, stream>>>(ctxv, v, accp, ml);
  k3_combine_bcast<<<256, 128, 0, stream>>>(accp, ml, out);
}

// Round 3
// 421.666 us; speedup vs baseline: 1.0262x; 1.0262x over previous
//
#include <hip/hip_runtime.h>
#include <math.h>

// Problem constants (fixed by the reference)
#define NB 32       // batch
#define ND 1024     // CTX_DIM
#define NC 2048     // CTX_SIZE
#define NH 1024     // HID
#define NSEQ 64     // seqlen
#define CCHUNK 32   // c-tile width per block (32 c = 128 B rows: full L2 lines)
#define NCHUNK (NC / CCHUNK)   // 64 chunks per batch

// async global -> LDS, 16 B per lane, dest = wave-uniform base + lane*16
#define GLD_TO_LDS(g, l)                                                     \
  __builtin_amdgcn_global_load_lds(                                          \
      (const __attribute__((address_space(1))) void*)(g),                    \
      (__attribute__((address_space(3))) void*)(l), 16, 0, 0)

// ---------------------------------------------------------------------------
// k1: v[b,d] = sum_h hidden[b,h] * W[h,d]   (bias is softmax-invariant: dropped)
// grid = 32 b * 8 dchunks(128) = 256 blocks, 128 threads. W is L2-resident.
// ---------------------------------------------------------------------------
__global__ __launch_bounds__(128) void k1_v(const float* __restrict__ hidden,
                                            const float* __restrict__ W,
                                            float* __restrict__ v) {
  const int b = blockIdx.x >> 3;
  const int d = ((blockIdx.x & 7) << 7) + threadIdx.x;
  const float* hb = hidden + b * NH;
  float acc = 0.f;
#pragma unroll 16
  for (int h = 0; h < NH; ++h) acc += hb[h] * W[h * ND + d];
  v[b * ND + d] = acc;
}

// ---------------------------------------------------------------------------
// k2: fused scores + chunk-local softmax + weighted partial sums.
// One block per (b, 32-wide c-chunk). Tile [d][c] = 1024x32 fp32 = 128 KB LDS
// (1 block/CU, 8 waves). Each d-row is one full 128 B line -> no over-fetch.
// Staging via global_load_lds dwordx4: tile word index == 4*tid exactly.
// Outputs: accp[bid][d] = sum_c exp(s_c - m)*ctx[b,d,c];  ml[bid] = {m, l}
// ---------------------------------------------------------------------------
__global__ __launch_bounds__(512) void k2_main(const float* __restrict__ ctx,
                                               const float* __restrict__ v,
                                               float* __restrict__ accp,
                                               float* __restrict__ ml) {
  __shared__ __align__(16) float tile[ND * CCHUNK];  // 128 KB, word = d*32 + c
  __shared__ __align__(16) float sred[64 * 32];      // 8 KB score partials
  __shared__ __align__(16) float pf[CCHUNK];         // softmax weights

  const int t = threadIdx.x;           // 0..511
  const int bid = blockIdx.x;
  const int b = bid >> 6;              // / NCHUNK
  const int c0 = (bid & (NCHUNK - 1)) << 5;
  const int dp = t >> 3;               // 0..63  (d = dp + 64*j)
  const int cg = t & 7;                // c-group of 4 (8 groups = 32 c)
  const int w = __builtin_amdgcn_readfirstlane(t >> 6);  // wave id, uniform

  // --- Phase A: issue all async tile loads (16 per wave, no VGPR round-trip)
  // lane l of wave w lands at word 256*w + 4*l + 2048*j == 4*t + 2048*j.
  const float* gbase = ctx + (size_t)b * ND * NC + (size_t)dp * NC + c0 + cg * 4;
#pragma unroll
  for (int j = 0; j < 16; ++j) {
    GLD_TO_LDS(gbase + (size_t)(64 * NC) * j, tile + 2048 * j + (w << 8));
  }

  // preload v fragments straight from global (L2-hot, 8-lane broadcast)
  float vsr[16];
#pragma unroll
  for (int j = 0; j < 16; ++j) vsr[j] = v[b * ND + dp + 64 * j];

  __syncthreads();  // drains the global_load_lds queue

  // --- Phase B: score partials from the LDS tile (contiguous 16 B per lane)
  float4 s4 = make_float4(0.f, 0.f, 0.f, 0.f);
  const float* myw = tile + 4 * t;
#pragma unroll
  for (int j = 0; j < 16; ++j) {
    float4 x = *(const float4*)(myw + 2048 * j);
    float vd = vsr[j];
    s4.x += x.x * vd; s4.y += x.y * vd; s4.z += x.z * vd; s4.w += x.w * vd;
  }
  *(float4*)(sred + 4 * t) = s4;   // sred[dp][cg*4 .. cg*4+3]
  __syncthreads();

  // --- chunk-local softmax over 32 c's (lanes 0..31: bank = c, conflict-free)
  if (t < 32) {
    float s = 0.f;
#pragma unroll
    for (int q = 0; q < 64; ++q) s += sred[32 * q + t];
    float mm = s;
#pragma unroll
    for (int off = 16; off; off >>= 1) mm = fmaxf(mm, __shfl_xor(mm, off, 32));
    float e = __expf(s - mm);
    float l = e;
#pragma unroll
    for (int off = 16; off; off >>= 1) l += __shfl_xor(l, off, 32);
    pf[t] = e;
    if (t == 0) { ml[bid * 2] = mm; ml[bid * 2 + 1] = l; }
  }
  __syncthreads();

  // --- Phase C: acc[d] = sum_c p[c] * tile[d*32+c], rotated bank groups
  // (8 lanes cover all 8 groups once -> 2-way alias over 16 lanes = free)
  float4 pr[8];
#pragma unroll
  for (int j = 0; j < 8; ++j)
    pr[j] = *(const float4*)(pf + (((j + t) & 7) << 2));

  float* ao = accp + (size_t)bid * ND;
#pragma unroll
  for (int k = 0; k < 2; ++k) {
    const int d = t + 512 * k;
    const float* tr = tile + d * CCHUNK;
    float a = 0.f;
#pragma unroll
    for (int j = 0; j < 8; ++j) {
      const int jr = (j + t) & 7;
      float4 x = *(const float4*)(tr + jr * 4);
      float4 pp = pr[j];
      a += x.x * pp.x + x.y * pp.y + x.z * pp.z + x.w * pp.w;
    }
    ao[d] = a;
  }
}

// ---------------------------------------------------------------------------
// k3: online-softmax combine across 64 chunks + broadcast to out[s,b,d].
// grid = 32 b * 8 d-slices(128) = 256 blocks, 128 threads.
// ---------------------------------------------------------------------------
__global__ __launch_bounds__(128) void k3_combine_bcast(
    const float* __restrict__ accp, const float* __restrict__ ml,
    float* __restrict__ out) {
  __shared__ float sc[NCHUNK];
  __shared__ float sinv_s;
  const int b = blockIdx.x >> 3;
  const int dslice = blockIdx.x & 7;
  const int t = threadIdx.x;           // 0..127

  if (t < NCHUNK) {                    // one wave does the combine math
    float mi = ml[(b * NCHUNK + t) * 2];
    float li = ml[(b * NCHUNK + t) * 2 + 1];
    float mg = mi;
#pragma unroll
    for (int off = 32; off; off >>= 1) mg = fmaxf(mg, __shfl_xor(mg, off, 64));
    float scale = __expf(mi - mg);
    float dpart = scale * li;
#pragma unroll
    for (int off = 32; off; off >>= 1) dpart += __shfl_xor(dpart, off, 64);
    sc[t] = scale;
    if (t == 0) sinv_s = 1.0f / dpart;
  }
  __syncthreads();
  const float sinv = sinv_s;

  const int d = dslice * 128 + t;
  const float* ap = accp + (size_t)b * NCHUNK * ND + d;
  float acc = 0.f;
#pragma unroll 16
  for (int i = 0; i < NCHUNK; ++i) acc += sc[i] * ap[(size_t)i * ND];
  acc *= sinv;

  float* op = out + b * ND + d;
#pragma unroll 8
  for (int s = 0; s < NSEQ; ++s) op[(size_t)s * NB * ND] = acc;
}

extern "C" void kernel_launch(void* const* d_in, const int* in_sizes, int n_in,
                              void* d_out, int out_size, void* d_ws, size_t ws_size,
                              hipStream_t stream) {
  (void)in_sizes; (void)n_in; (void)out_size; (void)ws_size;
  // d_in: [0]=seqlen(int,1) [1]=hidden(1,32,1024) [2]=contextvects(32,1024,2048)
  //       [3]=W(1024,1024) [4]=b(1024)  -- bias unused (softmax-invariant).
  const float* hidden = (const float*)d_in[1];
  const float* ctxv   = (const float*)d_in[2];
  const float* W      = (const float*)d_in[3];
  float* out = (float*)d_out;

  char* ws = (char*)d_ws;
  float* v    = (float*)(ws);                    // 32*1024 fp32   = 128 KB
  float* ml   = (float*)(ws + 131072);           // 2048*2 fp32    =  16 KB
  float* accp = (float*)(ws + 131072 + 16384);   // 2048*1024 fp32 =   8 MB

  k1_v<<<256, 128, 0, stream>>>(hidden, W, v);
  k2_main<<<NB * NCHUNK, 512, 0, stream>>>(ctxv, v, accp, ml);
  k3_combine_bcast<<<256, 128, 0, stream>>>(accp, ml, out);
}